// Round 8
// baseline (168.775 us; speedup 1.0000x reference)
//
#include <hip/hip_runtime.h>
#include <hip/hip_bf16.h>

// FixedChannelDP via Toeplitz-GEMM on bf16 MFMA 32x32x16.
// y[p,n] = sum_{k=0}^{512} h[k] x[p,n-k]  ('full' conv), out fp32 [2,NOUT,2].
//
// Round 8: BARRIER-FREE STREAMING MFMA. Rounds 0-7 (7 structures) all pinned
// at 46-63us because LDS staging of x forces per-tile barriers that convoy
// every wave onto the sum of phase floors. Fix: a ~10us bandwidth pre-pass
// (cvt_pad) writes x as ZERO-PADDED bf16 planes into the workspace; the main
// kernel (fir_direct) then streams A-fragments DIRECTLY from global memory
// (64 lanes x 16B at 64B stride = coalesced; window ~12KB/wave is L1/L2
// resident), with h in LDS (19KB, single barrier at kernel start). No LDS-x,
// no in-loop cvt, no ds_write, no steady-state barriers: independent waves,
// unroll-2 register ping-pong, latency hidden by 3 waves/SIMD TLP.
// Fallback to the proven round-2 kernel if ws_size is too small.
//
// Mapping per wave (strip s, b in [0,34)):
//   D[r][c] += sum_k A_b[r][k] * B_b[k][c],  n = s*1024 + 32r + c
//   A_b[r][k] = x[n + k + 16 - 16b]          (8 contig bf16 -> dwordx4 load)
//   B_b[k][c] = h[16b + c - k - 16] (0 OOB)  -> tap covered exactly once
// h table: hh[tab][R][j] = h[R-24-j]; row read at R = 16b + cc - 8*half + 8;
// rows >= 544 all-zero (b+1 prefetch safe).  re-part uses xi*(-hi) via v_xor.

#define NSAMP 4194304
#define LTAPS 513
#define NOUT  (NSAMP + LTAPS - 1)   // 4194816

#define NB     34
#define HROWS  592
#define PAD    1024
#define PLN    (PAD + NSAMP + PAD)          // 4196352 elems per plane
#define NSTRIP 4097                          // ceil(NOUT/1024)
#define BLK    256

#define PLANE_OFF  32768                     // planes byte offset in ws
#define WS_NEED    ((size_t)PLANE_OFF + 4ull * PLN * 2ull)   // ~33.6 MB

typedef __attribute__((ext_vector_type(8)))  short short8;
typedef __attribute__((ext_vector_type(4)))  short short4v;
typedef __attribute__((ext_vector_type(4)))  int   int4v;
typedef __attribute__((ext_vector_type(16))) float float16v;

__device__ __forceinline__ short f2b(float f) {
    __bf16 b = (__bf16)f;
    return __builtin_bit_cast(short, b);
}

__global__ __launch_bounds__(BLK)
void build_h(const float* __restrict__ hr, const float* __restrict__ hi,
             short* __restrict__ hh) {
    int R = blockIdx.x * BLK + threadIdx.x;
    if (R < HROWS) {
        short8 vr, vi;
        #pragma unroll
        for (int j = 0; j < 8; ++j) {
            int idx = R - 24 - j;
            bool ok = (idx >= 0) && (idx < LTAPS);
            vr[j] = f2b(ok ? hr[idx] : 0.0f);
            vi[j] = f2b(ok ? hi[idx] : 0.0f);
        }
        *(short8*)(hh + (size_t)(0 * HROWS + R) * 8) = vr;
        *(short8*)(hh + (size_t)(1 * HROWS + R) * 8) = vi;
    }
}

// ---- pre-pass: fp32 -> zero-padded bf16 planes -------------------------
// plane p: p&1 ? imag : real, pol = p>>1; layout [PAD zeros][NSAMP][PAD zeros]
#define UNITS_PER_PLANE (PLN / 8)            // 524544 16B-units
#define CVT_BLOCKS      ((4 * UNITS_PER_PLANE) / BLK)   // 8196 exactly

__global__ __launch_bounds__(BLK)
void cvt_pad(const float* __restrict__ txr, const float* __restrict__ txi,
             short* __restrict__ planes) {
    int u = blockIdx.x * BLK + threadIdx.x;   // [0, 4*UNITS_PER_PLANE)
    int p = u / UNITS_PER_PLANE;
    int q = u - p * UNITS_PER_PLANE;
    const float* __restrict__ src = ((p & 1) ? txi : txr) + (size_t)(p >> 1) * NSAMP;
    int e0 = q * 8 - PAD;
    short8 v;
    if (e0 >= 0 && e0 + 8 <= NSAMP) {
        float4 a = *(const float4*)(src + e0);
        float4 b = *(const float4*)(src + e0 + 4);
        v[0] = f2b(a.x); v[1] = f2b(a.y); v[2] = f2b(a.z); v[3] = f2b(a.w);
        v[4] = f2b(b.x); v[5] = f2b(b.y); v[6] = f2b(b.z); v[7] = f2b(b.w);
    } else {
        #pragma unroll
        for (int j = 0; j < 8; ++j) {
            int g = e0 + j;
            v[j] = (g >= 0 && g < NSAMP) ? f2b(src[g]) : (short)0;
        }
    }
    *(short8*)(planes + (size_t)p * PLN + (size_t)q * 8) = v;
}

#define MFMA32(A, B, C) __builtin_amdgcn_mfma_f32_32x32x16_bf16((A), (B), (C), 0, 0, 0)

__device__ __forceinline__ short8 bneg8(short8 v) {
    int4v t = __builtin_bit_cast(int4v, v);
    t ^= (int4v){(int)0x80008000, (int)0x80008000, (int)0x80008000, (int)0x80008000};
    return __builtin_bit_cast(short8, t);
}

// ---- main: barrier-free streaming MFMA ---------------------------------
__global__ __launch_bounds__(BLK, 3)
void fir_direct(const short* __restrict__ planes, const short* __restrict__ hh,
                float2* __restrict__ out) {
    __shared__ __align__(16) short hl[2 * HROWS * 8];   // 18,944 B

    const int tid = threadIdx.x;
    {   // h table -> LDS (2368 int4 units)
        const int4* src = (const int4*)hh;
        int4* dst = (int4*)hl;
        #pragma unroll
        for (int it = 0; it < 10; ++it) {
            int idx = tid + it * BLK;
            if (idx < (2 * HROWS * 8 * 2) / 16) dst[idx] = src[idx];
        }
    }
    __syncthreads();    // the only barrier in the kernel

    const int lane = tid & 63;
    const int wave = tid >> 6;
    const int cc   = lane & 31;     // A row r / B col c / D col
    const int half = lane >> 5;

    const int s = blockIdx.x * 4 + wave;       // strip index
    if (s >= NSTRIP) return;
    const int nw = s * 1024;

    const short* __restrict__ x0 = planes;                       // re pol0
    const short* __restrict__ x1 = planes + (size_t)PLN;         // im pol0
    const short* __restrict__ x2 = planes + (size_t)2 * PLN;     // re pol1
    const short* __restrict__ x3 = planes + (size_t)3 * PLN;     // im pol1

    // fragment element offset within a plane (b=0); decreases by 16 per b.
    // min over b: e0 - 544 >= PAD - 528 > 0; max: e0+7 <= PLN-1 (exact fit).
    const int    e0  = PAD + nw + 32 * cc + 8 * half + 16;
    const short* hp0 = hl + (size_t)(cc - 8 * half + 8) * 8;

    float16v zero = {0.f,0.f,0.f,0.f,0.f,0.f,0.f,0.f,0.f,0.f,0.f,0.f,0.f,0.f,0.f,0.f};
    float16v acc_re0 = zero, acc_im0 = zero, acc_re1 = zero, acc_im1 = zero;

    // prologue: fragments for b=0
    short8 fxr0 = *(const short8*)(x0 + e0);
    short8 fxi0 = *(const short8*)(x1 + e0);
    short8 fxr1 = *(const short8*)(x2 + e0);
    short8 fxi1 = *(const short8*)(x3 + e0);
    short8 fhr  = *(const short8*)(hp0);
    short8 fhi  = *(const short8*)(hp0 + (size_t)HROWS * 8);

    #pragma unroll 2
    for (int b = 0; b < NB; ++b) {
        // prefetch b+1 operands (always in-bounds: pads / zero h rows)
        const int en = e0 - 16 * (b + 1);
        short8 nxr0 = *(const short8*)(x0 + en);
        short8 nxi0 = *(const short8*)(x1 + en);
        short8 nxr1 = *(const short8*)(x2 + en);
        short8 nxi1 = *(const short8*)(x3 + en);
        const short* hn = hp0 + (size_t)(16 * (b + 1)) * 8;
        short8 nhr = *(const short8*)(hn);
        short8 nhi = *(const short8*)(hn + (size_t)HROWS * 8);

        short8 fnhi = bneg8(fhi);       // re-part: xi * (-hi)
        acc_re0 = MFMA32(fxr0, fhr,  acc_re0);
        acc_im0 = MFMA32(fxi0, fhr,  acc_im0);
        acc_re1 = MFMA32(fxr1, fhr,  acc_re1);
        acc_im1 = MFMA32(fxi1, fhr,  acc_im1);
        acc_re0 = MFMA32(fxi0, fnhi, acc_re0);
        acc_im0 = MFMA32(fxr0, fhi,  acc_im0);
        acc_re1 = MFMA32(fxi1, fnhi, acc_re1);
        acc_im1 = MFMA32(fxr1, fhi,  acc_im1);

        fxr0 = nxr0; fxi0 = nxi0; fxr1 = nxr1; fxi1 = nxi1;
        fhr  = nhr;  fhi  = nhi;
    }

    // epilogue: D col = cc, row = (reg&3) + 8*(reg>>2) + 4*half
    float2* __restrict__ op0 = out;
    float2* __restrict__ op1 = out + (size_t)NOUT;
    #pragma unroll
    for (int v = 0; v < 16; ++v) {
        int row = (v & 3) + 8 * (v >> 2) + 4 * half;
        int n = nw + 32 * row + cc;
        if (n < NOUT) {
            op0[n] = make_float2(acc_re0[v], acc_im0[v]);
            op1[n] = make_float2(acc_re1[v], acc_im1[v]);
        }
    }
}

// ======================= fallback (round-2 kernel, proven) ==============
#define F_BLOCK_OUT 4096
#define F_HALO      512
#define F_XELEMS    (F_BLOCK_OUT + F_HALO + 16)   // 4624
#define F_XSZ       F_XELEMS
#define F_NBLK      ((NOUT + F_BLOCK_OUT - 1) / F_BLOCK_OUT)

__device__ __forceinline__ int f_xswz(int e) { return e ^ (((e >> 6) & 7) << 3); }

__global__ __launch_bounds__(BLK, 4)
void fir_fb(const float* __restrict__ txr_all, const float* __restrict__ txi_all,
            const short* __restrict__ hh, float2* __restrict__ out) {
    const int N0  = blockIdx.x * F_BLOCK_OUT;
    const int tid = threadIdx.x;
    __shared__ __align__(16) short xs[4][F_XSZ];

    #pragma unroll
    for (int p = 0; p < 2; ++p) {
        const float* __restrict__ xr_g = txr_all + (size_t)p * NSAMP;
        const float* __restrict__ xi_g = txi_all + (size_t)p * NSAMP;
        #pragma unroll
        for (int it = 0; it < 5; ++it) {
            int e = (tid + it * BLK) * 4;
            if (e < F_XELEMS) {
                int g = N0 - F_HALO + e;
                float r0, r1, r2, r3, i0, i1, i2, i3;
                if (g >= 0 && g + 3 < NSAMP) {
                    float4 fr = *(const float4*)(xr_g + g);
                    float4 fi = *(const float4*)(xi_g + g);
                    r0 = fr.x; r1 = fr.y; r2 = fr.z; r3 = fr.w;
                    i0 = fi.x; i1 = fi.y; i2 = fi.z; i3 = fi.w;
                } else {
                    int gc0 = min(max(g + 0, 0), NSAMP - 1);
                    int gc1 = min(max(g + 1, 0), NSAMP - 1);
                    int gc2 = min(max(g + 2, 0), NSAMP - 1);
                    int gc3 = min(max(g + 3, 0), NSAMP - 1);
                    r0 = (g + 0 >= 0 && g + 0 < NSAMP) ? xr_g[gc0] : 0.0f;
                    r1 = (g + 1 >= 0 && g + 1 < NSAMP) ? xr_g[gc1] : 0.0f;
                    r2 = (g + 2 >= 0 && g + 2 < NSAMP) ? xr_g[gc2] : 0.0f;
                    r3 = (g + 3 >= 0 && g + 3 < NSAMP) ? xr_g[gc3] : 0.0f;
                    i0 = (g + 0 >= 0 && g + 0 < NSAMP) ? xi_g[gc0] : 0.0f;
                    i1 = (g + 1 >= 0 && g + 1 < NSAMP) ? xi_g[gc1] : 0.0f;
                    i2 = (g + 2 >= 0 && g + 2 < NSAMP) ? xi_g[gc2] : 0.0f;
                    i3 = (g + 3 >= 0 && g + 3 < NSAMP) ? xi_g[gc3] : 0.0f;
                }
                int ls = f_xswz(e);
                short4v vr = { f2b(r0), f2b(r1), f2b(r2), f2b(r3) };
                short4v vi = { f2b(i0), f2b(i1), f2b(i2), f2b(i3) };
                *(short4v*)(&xs[2 * p + 0][ls]) = vr;
                *(short4v*)(&xs[2 * p + 1][ls]) = vi;
            }
        }
    }
    __syncthreads();

    const int lane = tid & 63;
    const int wave = tid >> 6;
    const int cc   = lane & 31;
    const int half = lane >> 5;

    float16v zero = {0.f,0.f,0.f,0.f,0.f,0.f,0.f,0.f,0.f,0.f,0.f,0.f,0.f,0.f,0.f,0.f};
    float16v acc_re0 = zero, acc_im0 = zero, acc_re1 = zero, acc_im1 = zero;

    const int    ebase = F_HALO + wave * 1024 + 32 * cc + 8 * half + 16;
    const short* hpr   = hh + (size_t)(cc - 8 * half + 8) * 8;
    const short* xb    = &xs[0][0];

    int ls0 = f_xswz(ebase);
    short8 fxr0 = *(const short8*)(xb + ls0);
    short8 fxi0 = *(const short8*)(xb + F_XSZ + ls0);
    short8 fxr1 = *(const short8*)(xb + 2 * F_XSZ + ls0);
    short8 fxi1 = *(const short8*)(xb + 3 * F_XSZ + ls0);
    short8 fhr  = *(const short8*)(hpr);
    short8 fhi  = *(const short8*)(hpr + (size_t)HROWS * 8);

    #pragma unroll 2
    for (int b = 0; b < NB; ++b) {
        int en = ebase - 16 * (b + 1);
        en = en < 0 ? 0 : en;
        int lsn = f_xswz(en);
        short8 nxr0 = *(const short8*)(xb + lsn);
        short8 nxi0 = *(const short8*)(xb + F_XSZ + lsn);
        short8 nxr1 = *(const short8*)(xb + 2 * F_XSZ + lsn);
        short8 nxi1 = *(const short8*)(xb + 3 * F_XSZ + lsn);
        const short* hn = hpr + (size_t)(16 * (b + 1)) * 8;
        short8 nhr = *(const short8*)(hn);
        short8 nhi = *(const short8*)(hn + (size_t)HROWS * 8);

        short8 fnhi = bneg8(fhi);
        acc_re0 = MFMA32(fxr0, fhr,  acc_re0);
        acc_im0 = MFMA32(fxi0, fhr,  acc_im0);
        acc_re1 = MFMA32(fxr1, fhr,  acc_re1);
        acc_im1 = MFMA32(fxi1, fhr,  acc_im1);
        acc_re0 = MFMA32(fxi0, fnhi, acc_re0);
        acc_im0 = MFMA32(fxr0, fhi,  acc_im0);
        acc_re1 = MFMA32(fxi1, fnhi, acc_re1);
        acc_im1 = MFMA32(fxr1, fhi,  acc_im1);

        fxr0 = nxr0; fxi0 = nxi0; fxr1 = nxr1; fxi1 = nxi1;
        fhr  = nhr;  fhi  = nhi;
    }

    float2* __restrict__ op0 = out;
    float2* __restrict__ op1 = out + (size_t)NOUT;
    const int nw = N0 + wave * 1024;
    #pragma unroll
    for (int v = 0; v < 16; ++v) {
        int row = (v & 3) + 8 * (v >> 2) + 4 * half;
        int n = nw + 32 * row + cc;
        if (n < NOUT) {
            op0[n] = make_float2(acc_re0[v], acc_im0[v]);
            op1[n] = make_float2(acc_re1[v], acc_im1[v]);
        }
    }
}

extern "C" void kernel_launch(void* const* d_in, const int* in_sizes, int n_in,
                              void* d_out, int out_size, void* d_ws, size_t ws_size,
                              hipStream_t stream) {
    const float* txr = (const float*)d_in[0];
    const float* txi = (const float*)d_in[1];
    const float* hr  = (const float*)d_in[2];
    const float* hi  = (const float*)d_in[3];
    float2* out = (float2*)d_out;
    short* hh = (short*)d_ws;   // 2 * 592 * 8 bf16 ≈ 19 KB

    build_h<<<dim3((HROWS + BLK - 1) / BLK), BLK, 0, stream>>>(hr, hi, hh);

    if (ws_size >= WS_NEED) {
        short* planes = (short*)((char*)d_ws + PLANE_OFF);
        cvt_pad<<<dim3(CVT_BLOCKS), BLK, 0, stream>>>(txr, txi, planes);
        fir_direct<<<dim3((NSTRIP + 3) / 4), BLK, 0, stream>>>(planes, hh, out);
    } else {
        fir_fb<<<dim3(F_NBLK), BLK, 0, stream>>>(txr, txi, hh, out);
    }
}